// Round 1
// baseline (1639.252 us; speedup 1.0000x reference)
//
#include <hip/hip_runtime.h>
#include <math.h>

#define B_SZ 32768
#define D_SZ 1024
#define R_SZ 64
#define E_SZ 4
#define L_SZ 3
#define NC   256          // E*R
#define TBA  16           // rows per block, stage 1
#define TBB  16           // rows per block, stage 2

// Ut[l][e][s][d] = U[l][e][d][s]  (so stage-2 dot over c=(e,s) reads coalesced rows)
__global__ __launch_bounds__(256) void transpose_u(const float* __restrict__ U,
                                                   float* __restrict__ Ut) {
    int idx = blockIdx.x * 256 + threadIdx.x;        // < L*E*R*D = 786432
    int d = idx & (D_SZ - 1);
    int rest = idx >> 10;                            // le*R + s
    int s = rest & (R_SZ - 1);
    int le = rest >> 6;
    Ut[idx] = U[((size_t)le * D_SZ + d) * R_SZ + s];
}

// Stage 1: gating softmax + v1=tanh(xi@V) + v2=tanh(v1@C), emit w[b,c] = v2*score
__global__ __launch_bounds__(256) void cross_stage1(
    const float* xi, const float* __restrict__ G,
    const float* __restrict__ V, const float* __restrict__ C,
    float* __restrict__ w_out)
{
    // smem lifetimes: xs[16][1024] -> red[4][16][256] -> v1[16][256] (in place)
    __shared__ float smem[16 * 1024];
    __shared__ float ssc[TBA][E_SZ];

    const int t = threadIdx.x;
    const int b0 = blockIdx.x * TBA;

    // stage xi tile (contiguous 16*1024 floats)
    {
        const float4* src = (const float4*)(xi + (size_t)b0 * D_SZ);
        float4* dst = (float4*)smem;
        #pragma unroll
        for (int i = 0; i < 16; ++i) dst[t + i * 256] = src[t + i * 256];
    }
    __syncthreads();

    // ---- gating: thread (e=t>>6, r=t&63) partial over d = r+64k
    {
        const int ge = t >> 6, gr = t & 63;
        float g[TBA];
        #pragma unroll
        for (int row = 0; row < TBA; ++row) g[row] = 0.f;
        for (int k = 0; k < D_SZ / 64; ++k) {
            float gw = G[ge * D_SZ + gr + k * 64];
            #pragma unroll
            for (int row = 0; row < TBA; ++row)
                g[row] += smem[row * D_SZ + gr + k * 64] * gw;
        }
        #pragma unroll
        for (int off = 32; off; off >>= 1) {
            #pragma unroll
            for (int row = 0; row < TBA; ++row)
                g[row] += __shfl_down(g[row], off, 64);
        }
        if (gr == 0) {
            #pragma unroll
            for (int row = 0; row < TBA; ++row) ssc[row][ge] = g[row];
        }
    }
    __syncthreads();
    if (t < TBA) {  // softmax over E=4 per row
        float m = ssc[t][0];
        #pragma unroll
        for (int j = 1; j < E_SZ; ++j) m = fmaxf(m, ssc[t][j]);
        float den = 0.f, ex[E_SZ];
        #pragma unroll
        for (int j = 0; j < E_SZ; ++j) { ex[j] = __expf(ssc[t][j] - m); den += ex[j]; }
        float inv = 1.f / den;
        #pragma unroll
        for (int j = 0; j < E_SZ; ++j) ssc[t][j] = ex[j] * inv;
    }
    // (ssc consumed only after later barriers)

    // ---- v1: d-group dg = t>>6 covers d in [dg*256, dg*256+256),
    //          cq = t&63 owns columns 4cq..4cq+3 (never spans an expert boundary)
    const int dg = t >> 6, cq = t & 63;
    const int col4 = cq * 4;
    const int ev = col4 >> 6;
    const int r4 = col4 & 63;
    float4 acc[TBA];
    #pragma unroll
    for (int row = 0; row < TBA; ++row) acc[row] = make_float4(0.f, 0.f, 0.f, 0.f);
    const float* Vp = V + (size_t)ev * D_SZ * R_SZ + r4;
    const int dbase = dg * 256;
    for (int d0 = 0; d0 < 256; d0 += 4) {
        const float* vb = Vp + (size_t)(dbase + d0) * R_SZ;
        float4 wv0 = *(const float4*)(vb);
        float4 wv1 = *(const float4*)(vb + R_SZ);
        float4 wv2 = *(const float4*)(vb + 2 * R_SZ);
        float4 wv3 = *(const float4*)(vb + 3 * R_SZ);
        #pragma unroll
        for (int row = 0; row < TBA; ++row) {
            float4 xv = *(const float4*)&smem[row * D_SZ + dbase + d0];
            acc[row].x += xv.x * wv0.x; acc[row].y += xv.x * wv0.y;
            acc[row].z += xv.x * wv0.z; acc[row].w += xv.x * wv0.w;
            acc[row].x += xv.y * wv1.x; acc[row].y += xv.y * wv1.y;
            acc[row].z += xv.y * wv1.z; acc[row].w += xv.y * wv1.w;
            acc[row].x += xv.z * wv2.x; acc[row].y += xv.z * wv2.y;
            acc[row].z += xv.z * wv2.z; acc[row].w += xv.z * wv2.w;
            acc[row].x += xv.w * wv3.x; acc[row].y += xv.w * wv3.y;
            acc[row].z += xv.w * wv3.z; acc[row].w += xv.w * wv3.w;
        }
    }
    __syncthreads();   // xs now dead
    // scatter partials red[dg][row][col4..col4+3]
    #pragma unroll
    for (int row = 0; row < TBA; ++row)
        *(float4*)&smem[dg * 4096 + row * NC + col4] = acc[row];
    __syncthreads();
    // reduce 4 d-groups in place + tanh -> v1 at smem[row*256 + c]
    #pragma unroll
    for (int row = 0; row < TBA; ++row) {
        float v = smem[row * NC + t] + smem[4096 + row * NC + t]
                + smem[8192 + row * NC + t] + smem[12288 + row * NC + t];
        smem[row * NC + t] = tanhf(v);
    }
    __syncthreads();

    // ---- v2: output col r2 = t&63 of expert e2 = t>>6; sum over s
    const int e2 = t >> 6, r2 = t & 63;
    float acc2[TBA];
    #pragma unroll
    for (int row = 0; row < TBA; ++row) acc2[row] = 0.f;
    const float* Cp = C + e2 * R_SZ * R_SZ + r2;
    for (int s = 0; s < R_SZ; ++s) {
        float cw = Cp[s * R_SZ];
        #pragma unroll
        for (int row = 0; row < TBA; ++row)
            acc2[row] += smem[row * NC + e2 * 64 + s] * cw;
    }
    // w = tanh(acc2) * score  (coalesced per row)
    #pragma unroll
    for (int row = 0; row < TBA; ++row)
        w_out[(size_t)(b0 + row) * NC + t] = tanhf(acc2[row]) * ssc[row][e2];
}

// Stage 2: out[b,d] = x0[b,d]*( sum_c w[b,c]*Ut[c,d] + bias[d] ) + xi[b,d]
__global__ __launch_bounds__(256) void cross_stage2(
    const float* __restrict__ w_in, const float* __restrict__ Ut,
    const float* __restrict__ bias, const float* __restrict__ x0,
    const float* xi, float* out)   // xi may alias out (same-thread read-then-write)
{
    __shared__ float wbuf[TBB * NC];
    const int t = threadIdx.x;
    const int b0 = blockIdx.x * TBB;
    {
        const float4* src = (const float4*)(w_in + (size_t)b0 * NC);
        float4* dst = (float4*)wbuf;
        #pragma unroll
        for (int i = 0; i < TBB * NC / 4 / 256; ++i) dst[t + i * 256] = src[t + i * 256];
    }
    __syncthreads();
    float4 acc[TBB];
    #pragma unroll
    for (int row = 0; row < TBB; ++row) acc[row] = make_float4(0.f, 0.f, 0.f, 0.f);
    const float4* Up = (const float4*)Ut + t;     // thread owns d = 4t..4t+3
    #pragma unroll 2
    for (int c = 0; c < NC; ++c) {
        float4 u4 = Up[c * (D_SZ / 4)];
        #pragma unroll
        for (int row = 0; row < TBB; ++row) {
            float wv = wbuf[row * NC + c];        // wave-broadcast LDS read
            acc[row].x += wv * u4.x; acc[row].y += wv * u4.y;
            acc[row].z += wv * u4.z; acc[row].w += wv * u4.w;
        }
    }
    float4 b4 = ((const float4*)bias)[t];
    #pragma unroll
    for (int row = 0; row < TBB; ++row) {
        size_t off = (size_t)(b0 + row) * (D_SZ / 4) + t;
        float4 xv = ((const float4*)x0)[off];
        float4 yv = ((const float4*)xi)[off];
        float4 o;
        o.x = xv.x * (acc[row].x + b4.x) + yv.x;
        o.y = xv.y * (acc[row].y + b4.y) + yv.y;
        o.z = xv.z * (acc[row].z + b4.z) + yv.z;
        o.w = xv.w * (acc[row].w + b4.w) + yv.w;
        ((float4*)out)[off] = o;
    }
}

extern "C" void kernel_launch(void* const* d_in, const int* in_sizes, int n_in,
                              void* d_out, int out_size, void* d_ws, size_t ws_size,
                              hipStream_t stream) {
    const float* x  = (const float*)d_in[0];
    const float* U  = (const float*)d_in[1];
    const float* V  = (const float*)d_in[2];
    const float* C  = (const float*)d_in[3];
    const float* bi = (const float*)d_in[4];
    const float* G  = (const float*)d_in[5];
    float* out  = (float*)d_out;
    float* w_ws = (float*)d_ws;                    // B*NC floats   (32 MB)
    float* Ut   = w_ws + (size_t)B_SZ * NC;        // L*E*R*D floats (3 MB)

    transpose_u<<<(L_SZ * E_SZ * R_SZ * D_SZ) / 256, 256, 0, stream>>>(U, Ut);
    for (int l = 0; l < L_SZ; ++l) {
        const float* xil = (l == 0) ? x : out;
        cross_stage1<<<B_SZ / TBA, 256, 0, stream>>>(
            xil, G,
            V + (size_t)l * E_SZ * D_SZ * R_SZ,
            C + (size_t)l * E_SZ * R_SZ * R_SZ,
            w_ws);
        cross_stage2<<<B_SZ / TBB, 256, 0, stream>>>(
            w_ws,
            Ut + (size_t)l * E_SZ * R_SZ * D_SZ,
            bi + (size_t)l * D_SZ,
            x, xil, out);
    }
}

// Round 2
// 996.217 us; speedup vs baseline: 1.6455x; 1.6455x over previous
//
#include <hip/hip_runtime.h>
#include <math.h>

#define B_SZ 32768
#define D_SZ 1024
#define R_SZ 64
#define E_SZ 4
#define L_SZ 3
#define NC   256          // E*R
#define TR   64           // rows per block
#define NTHR 512          // 8 waves

typedef __attribute__((ext_vector_type(8))) short bf16x8;
typedef __attribute__((ext_vector_type(4))) float f32x4;

__device__ __forceinline__ short f2bf(float f) {
    union { float f; unsigned u; } c; c.f = f;
    unsigned r = c.u + 0x7fffu + ((c.u >> 16) & 1u);   // round-to-nearest-even
    return (short)(r >> 16);
}

// Vt[l][c][d] = bf16(V[l][e][d][r]), c = e*64+r   (B-operand for v1: k=d contiguous)
__global__ __launch_bounds__(256) void pack_vt(const float* __restrict__ V,
                                               short* __restrict__ Vt) {
    int idx = blockIdx.x * 256 + threadIdx.x;          // L*256*1024
    int d = idx & 1023;
    int c = (idx >> 10) & 255;
    int l = idx >> 18;
    int e = c >> 6, r = c & 63;
    Vt[idx] = f2bf(V[((size_t)(l * E_SZ + e) * D_SZ + d) * R_SZ + r]);
}
// Ub[l][d][c] = bf16(U[l][e][d][s]), c = e*64+s    (B-operand for uv: k=c contiguous)
__global__ __launch_bounds__(256) void pack_ub(const float* __restrict__ U,
                                               short* __restrict__ Ub) {
    int idx = blockIdx.x * 256 + threadIdx.x;          // L*1024*256
    int c = idx & 255;
    int d = (idx >> 8) & 1023;
    int l = idx >> 18;
    int e = c >> 6, s = c & 63;
    Ub[idx] = f2bf(U[((size_t)(l * E_SZ + e) * D_SZ + d) * R_SZ + s]);
}
// Ct[l][e][s][r] = bf16(C[l][e][r][s])             (B-operand for v2: k=r contiguous)
__global__ __launch_bounds__(256) void pack_ct(const float* __restrict__ C,
                                               short* __restrict__ Ct) {
    int idx = blockIdx.x * 256 + threadIdx.x;          // L*4*64*64
    int r = idx & 63;
    int s = (idx >> 6) & 63;
    int le = idx >> 12;
    Ct[idx] = f2bf(C[((size_t)le * R_SZ + r) * R_SZ + s]);
}

// One fused cross layer: gating + v1 + v2 + w@U^T + epilogue, bf16 MFMA.
__global__ __launch_bounds__(NTHR, 2) void cross_layer(
    const float* xi,                       // may alias out (in-place per-thread)
    const float* __restrict__ x0,
    const float* __restrict__ G,
    const short* __restrict__ Vt, const short* __restrict__ Ub,
    const short* __restrict__ Ct, const float* __restrict__ bias,
    float* out)
{
    __shared__ short xs[TR * 136];   // xi chunk, bf16, row stride 136 (pad: 2-way banks)
    __shared__ short wb[TR * 264];   // v1 then w, bf16, row stride 264
    __shared__ float ssc[TR * E_SZ]; // softmax scores

    const int t = threadIdx.x;
    const int b0 = blockIdx.x * TR;
    const int lane = t & 63;
    const int wv = t >> 6;           // wave 0..7
    const int m = lane & 15;         // A-row / B-col / C-col index
    const int q = lane >> 4;         // quad

    // ---------------- phase 0: gating (VALU, xi from global) ----------------
    {
        float* gred = (float*)wb;    // overlay [64][8][4], dead before v1 writes
        const int row = t >> 3, j = t & 7;
        const float4* xr = (const float4*)(xi + (size_t)(b0 + row) * D_SZ + j * 128);
        const float4* G0 = (const float4*)(G + 0 * D_SZ + j * 128);
        const float4* G1 = (const float4*)(G + 1 * D_SZ + j * 128);
        const float4* G2 = (const float4*)(G + 2 * D_SZ + j * 128);
        const float4* G3 = (const float4*)(G + 3 * D_SZ + j * 128);
        float g0 = 0.f, g1 = 0.f, g2 = 0.f, g3 = 0.f;
        #pragma unroll 4
        for (int i = 0; i < 32; ++i) {
            float4 xv = xr[i];
            float4 a = G0[i], b = G1[i], c = G2[i], d = G3[i];
            g0 += xv.x * a.x + xv.y * a.y + xv.z * a.z + xv.w * a.w;
            g1 += xv.x * b.x + xv.y * b.y + xv.z * b.z + xv.w * b.w;
            g2 += xv.x * c.x + xv.y * c.y + xv.z * c.z + xv.w * c.w;
            g3 += xv.x * d.x + xv.y * d.y + xv.z * d.z + xv.w * d.w;
        }
        float* gp = gred + (row * 8 + j) * 4;
        gp[0] = g0; gp[1] = g1; gp[2] = g2; gp[3] = g3;
        __syncthreads();
        if (t < TR) {
            float lg[E_SZ];
            #pragma unroll
            for (int e = 0; e < E_SZ; ++e) {
                float s = 0.f;
                #pragma unroll
                for (int jj = 0; jj < 8; ++jj) s += gred[(t * 8 + jj) * 4 + e];
                lg[e] = s;
            }
            float mx = fmaxf(fmaxf(lg[0], lg[1]), fmaxf(lg[2], lg[3]));
            float den = 0.f, ex[E_SZ];
            #pragma unroll
            for (int e = 0; e < E_SZ; ++e) { ex[e] = __expf(lg[e] - mx); den += ex[e]; }
            float inv = 1.f / den;
            #pragma unroll
            for (int e = 0; e < E_SZ; ++e) ssc[t * E_SZ + e] = ex[e] * inv;
        }
        __syncthreads();
    }

    // ---------------- phase V: v1 = tanh(xi @ V), wave -> 32 cols ----------------
    f32x4 accV[4][2];
    #pragma unroll
    for (int rt = 0; rt < 4; ++rt)
        #pragma unroll
        for (int ct = 0; ct < 2; ++ct) accV[rt][ct] = (f32x4){0.f, 0.f, 0.f, 0.f};
    const int cbase = wv * 32;
    for (int kc = 0; kc < 8; ++kc) {
        {   // stage chunk fp32 -> bf16 LDS
            const int row = t >> 3, j = t & 7;
            const float4* src = (const float4*)(xi + (size_t)(b0 + row) * D_SZ + kc * 128 + j * 16);
            short4* dst = (short4*)(xs + row * 136 + j * 16);
            #pragma unroll
            for (int p = 0; p < 4; ++p) {
                float4 v = src[p];
                short4 s;
                s.x = f2bf(v.x); s.y = f2bf(v.y); s.z = f2bf(v.z); s.w = f2bf(v.w);
                dst[p] = s;
            }
        }
        __syncthreads();
        #pragma unroll
        for (int ks = 0; ks < 4; ++ks) {
            bf16x8 a[4];
            #pragma unroll
            for (int rt = 0; rt < 4; ++rt)
                a[rt] = *(const bf16x8*)(xs + (rt * 16 + m) * 136 + ks * 32 + q * 8);
            #pragma unroll
            for (int ct = 0; ct < 2; ++ct) {
                bf16x8 b = *(const bf16x8*)(Vt + (size_t)(cbase + ct * 16 + m) * D_SZ
                                            + kc * 128 + ks * 32 + q * 8);
                #pragma unroll
                for (int rt = 0; rt < 4; ++rt)
                    accV[rt][ct] = __builtin_amdgcn_mfma_f32_16x16x32_bf16(
                        a[rt], b, accV[rt][ct], 0, 0, 0);
            }
        }
        __syncthreads();
    }
    // tanh -> wb (bf16, A-layout row-major)
    #pragma unroll
    for (int rt = 0; rt < 4; ++rt)
        #pragma unroll
        for (int ct = 0; ct < 2; ++ct)
            #pragma unroll
            for (int i = 0; i < 4; ++i) {
                int row = rt * 16 + q * 4 + i;
                int c = cbase + ct * 16 + m;
                wb[row * 264 + c] = f2bf(tanhf(accV[rt][ct][i]));
            }
    __syncthreads();

    // ---------------- phase C: v2 = tanh(v1 @ C_e), w = v2*score ----------------
    {
        const int e = wv >> 1, rh = wv & 1;       // wave -> (expert, row-half)
        f32x4 accC[2][4];
        #pragma unroll
        for (int r2 = 0; r2 < 2; ++r2)
            #pragma unroll
            for (int st = 0; st < 4; ++st) accC[r2][st] = (f32x4){0.f, 0.f, 0.f, 0.f};
        #pragma unroll
        for (int ks = 0; ks < 2; ++ks) {
            bf16x8 a[2];
            #pragma unroll
            for (int r2 = 0; r2 < 2; ++r2) {
                int rt = rh * 2 + r2;
                a[r2] = *(const bf16x8*)(wb + (rt * 16 + m) * 264 + e * 64 + ks * 32 + q * 8);
            }
            #pragma unroll
            for (int st = 0; st < 4; ++st) {
                bf16x8 b = *(const bf16x8*)(Ct + e * 4096 + (st * 16 + m) * 64 + ks * 32 + q * 8);
                #pragma unroll
                for (int r2 = 0; r2 < 2; ++r2)
                    accC[r2][st] = __builtin_amdgcn_mfma_f32_16x16x32_bf16(
                        a[r2], b, accC[r2][st], 0, 0, 0);
            }
        }
        #pragma unroll
        for (int r2 = 0; r2 < 2; ++r2)
            #pragma unroll
            for (int st = 0; st < 4; ++st)
                #pragma unroll
                for (int i = 0; i < 4; ++i) {
                    int row = (rh * 2 + r2) * 16 + q * 4 + i;
                    int s = st * 16 + m;
                    wb[row * 264 + e * 64 + s] =
                        f2bf(tanhf(accC[r2][st][i]) * ssc[row * E_SZ + e]);
                }
    }
    __syncthreads();

    // ---------------- phase U: uv = w @ U^T + epilogue, two d-halves ----------------
    #pragma unroll
    for (int hf = 0; hf < 2; ++hf) {
        const int dbase = hf * 512 + wv * 64;
        f32x4 accU[4][4];
        #pragma unroll
        for (int rt = 0; rt < 4; ++rt)
            #pragma unroll
            for (int dt = 0; dt < 4; ++dt) accU[rt][dt] = (f32x4){0.f, 0.f, 0.f, 0.f};
        #pragma unroll
        for (int ks = 0; ks < 8; ++ks) {
            bf16x8 a[4];
            #pragma unroll
            for (int rt = 0; rt < 4; ++rt)
                a[rt] = *(const bf16x8*)(wb + (rt * 16 + m) * 264 + ks * 32 + q * 8);
            #pragma unroll
            for (int dt = 0; dt < 4; ++dt) {
                bf16x8 b = *(const bf16x8*)(Ub + (size_t)(dbase + dt * 16 + m) * NC
                                            + ks * 32 + q * 8);
                #pragma unroll
                for (int rt = 0; rt < 4; ++rt)
                    accU[rt][dt] = __builtin_amdgcn_mfma_f32_16x16x32_bf16(
                        a[rt], b, accU[rt][dt], 0, 0, 0);
            }
        }
        #pragma unroll
        for (int rt = 0; rt < 4; ++rt)
            #pragma unroll
            for (int dt = 0; dt < 4; ++dt) {
                int d = dbase + dt * 16 + m;
                float bv = bias[d];
                #pragma unroll
                for (int i = 0; i < 4; ++i) {
                    int row = rt * 16 + q * 4 + i;
                    size_t off = (size_t)(b0 + row) * D_SZ + d;
                    out[off] = fmaf(x0[off], accU[rt][dt][i] + bv, xi[off]);
                }
            }
    }
}

extern "C" void kernel_launch(void* const* d_in, const int* in_sizes, int n_in,
                              void* d_out, int out_size, void* d_ws, size_t ws_size,
                              hipStream_t stream) {
    const float* x  = (const float*)d_in[0];
    const float* U  = (const float*)d_in[1];
    const float* V  = (const float*)d_in[2];
    const float* C  = (const float*)d_in[3];
    const float* bi = (const float*)d_in[4];
    const float* G  = (const float*)d_in[5];
    float* out = (float*)d_out;

    short* Vt = (short*)d_ws;                              // L*256*1024 bf16
    short* Ub = Vt + (size_t)L_SZ * NC * D_SZ;             // L*1024*256 bf16
    short* Ct = Ub + (size_t)L_SZ * D_SZ * NC;             // L*4*64*64 bf16

    pack_vt<<<(L_SZ * NC * D_SZ) / 256, 256, 0, stream>>>(V, Vt);
    pack_ub<<<(L_SZ * D_SZ * NC) / 256, 256, 0, stream>>>(U, Ub);
    pack_ct<<<(L_SZ * E_SZ * R_SZ * R_SZ) / 256, 256, 0, stream>>>(C, Ct);

    for (int l = 0; l < L_SZ; ++l) {
        const float* xil = (l == 0) ? x : out;
        cross_layer<<<B_SZ / TR, NTHR, 0, stream>>>(
            xil, x, G,
            Vt + (size_t)l * NC * D_SZ,
            Ub + (size_t)l * D_SZ * NC,
            Ct + (size_t)l * E_SZ * R_SZ * R_SZ,
            bi + (size_t)l * D_SZ,
            out);
    }
}